// Round 4
// baseline (413.132 us; speedup 1.0000x reference)
//
#include <hip/hip_runtime.h>

typedef __attribute__((ext_vector_type(8))) short bf16x8;
typedef __attribute__((ext_vector_type(4))) float f32x4;
typedef __attribute__((ext_vector_type(4))) unsigned short u16x4;

#define NEG 0.2f
#define CST 104            // bf16 elems per LDS row (208 B stride)
#define HELE 11776         // padded bf16 elems per head in Wbf (= 23552 B = 23*1024)

__device__ __forceinline__ float lrelu(float x) { return x >= 0.0f ? x : NEG * x; }

__device__ __forceinline__ unsigned short f2bf(float x) {
    unsigned u = __builtin_bit_cast(unsigned, x);
    u += 0x7FFFu + ((u >> 16) & 1u);
    return (unsigned short)(u >> 16);
}

// Wbf[h]: 112 rows x 104 cols bf16, row-major, 128-elem zero tail pad.
// rows 0..99 = W_h[o][f] (cols 100..103 = 0); row 100 = W_h^T att_src;
// row 101 = W_h^T att_dst; rows 102..111 = 0.
extern "C" __global__ void prep_w(const float* __restrict__ W,
                                  const float* __restrict__ att_src,
                                  const float* __restrict__ att_dst,
                                  unsigned short* __restrict__ Wbf)
{
    const int h = blockIdx.x;      // 4
    const int f = threadIdx.x;     // 128
    unsigned short* Wh = Wbf + h * HELE;
    float ws = 0.0f, wd = 0.0f;
    if (f < 100) {
        for (int o = 0; o < 100; ++o) {
            float wv = W[(h * 100 + o) * 100 + f];
            ws = fmaf(att_src[h * 100 + o], wv, ws);
            wd = fmaf(att_dst[h * 100 + o], wv, wd);
        }
    }
    if (f < CST) {
        for (int o = 0; o < 100; ++o)
            Wh[o * CST + f] = (f < 100) ? f2bf(W[(h * 100 + o) * 100 + f]) : (unsigned short)0;
        Wh[100 * CST + f] = (f < 100) ? f2bf(ws) : (unsigned short)0;
        Wh[101 * CST + f] = (f < 100) ? f2bf(wd) : (unsigned short)0;
        for (int o = 102; o < 112; ++o) Wh[o * CST + f] = 0;
    }
    Wh[11648 + f] = 0;   // 128-elem pad tail
}

// LDS map (bytes):
//   P  @ 0     : 23296  (X[n][f], then E[i][j] per head)      [112][104] bf16
//   HT @ 23296 : 23296  (H^T[o][j])                           [112][104] bf16
//   Q  @ 46592 : 23552  (W stage, padded)
//   tails @ 70144: sas[112] sad[112] ssi[112] sp[2][112] f32 = 2240
//   total 72384 B -> 2 blocks/CU
//   sOut f32 [112][104] overlays P+HT at the end (46592 B).
extern "C" __global__ void __launch_bounds__(256, 2)
gat4(const float* __restrict__ A, const unsigned short* __restrict__ Wbf,
     const float* __restrict__ bias, float* __restrict__ out)
{
    extern __shared__ char smem[];
    unsigned short* P  = (unsigned short*)(smem);
    unsigned short* HT = (unsigned short*)(smem + 23296);
    unsigned short* Q  = (unsigned short*)(smem + 46592);
    float* sas = (float*)(smem + 70144);
    float* sad = sas + 112;
    float* ssi = sad + 112;
    float* sp  = ssi + 112;            // [2][112]
    float* sOut = (float*)smem;        // [o][104] overlay

    const int t   = blockIdx.x;
    const int tid = threadIdx.x;
    const int w   = tid >> 6;
    const int l   = tid & 63;
    const int lr  = l & 15;
    const int lk  = l >> 4;
    const float* __restrict__ At = A + (size_t)t * 10000u;

    // ---- issue W[0] stage into Q (async, drains before first use) ----
    {
        const char* W0 = (const char*)Wbf;
        for (int c = w; c < 23; c += 4)
            __builtin_amdgcn_global_load_lds(
                (const __attribute__((address_space(1))) unsigned int*)(W0 + c * 1024 + l * 16),
                (__attribute__((address_space(3))) unsigned int*)(smem + 46592 + c * 1024),
                16, 0, 0);
    }

    // ---- zero P + HT (2912 f32x4) and tails (140 f32x4) ----
    for (int i = tid; i < 2912; i += 256) ((f32x4*)smem)[i] = (f32x4){0, 0, 0, 0};
    for (int i = tid; i < 140; i += 256) ((f32x4*)(smem + 70144))[i] = (f32x4){0, 0, 0, 0};
    __syncthreads();

    // ---- stage A_t^T -> P[n][f] bf16 (nontemporal reads protect L2) ----
    for (int idx = tid; idx < 10000; idx += 256) {
        int f = idx / 100, n = idx - f * 100;
        P[n * CST + f] = f2bf(__builtin_nontemporal_load(At + idx));
    }
    asm volatile("s_waitcnt vmcnt(0)" ::: "memory");   // W[0] stage landed
    __syncthreads();

    // ---- persistent A-fragments from P (X) ----
    const int nrow = (w < 3) ? 2 : 1;
    const int row0 = w, row1 = w + 4;
    const bf16x8 zf = {0, 0, 0, 0, 0, 0, 0, 0};
    bf16x8 xf[2][4];
#pragma unroll
    for (int ks = 0; ks < 4; ++ks) {
        const bool kill = (ks == 3) && (lk != 0);
        const int koff = kill ? 96 : ks * 32 + lk * 8;
        bf16x8 v0 = *(const bf16x8*)(P + (row0 * 16 + lr) * CST + koff);
        bf16x8 v1 = (nrow > 1) ? *(const bf16x8*)(P + (row1 * 16 + lr) * CST + koff) : v0;
        xf[0][ks] = kill ? zf : v0;
        xf[1][ks] = kill ? zf : v1;
    }

    f32x4 acc[2][7];
#pragma unroll
    for (int r = 0; r < 2; ++r)
#pragma unroll
        for (int c = 0; c < 7; ++c) acc[r][c] = (f32x4){0, 0, 0, 0};

    for (int h = 0; h < 4; ++h) {
        // ---- GEMM-1: c1 = X * W_h^T (B from Q) ----
        f32x4 c1[2][7];
#pragma unroll
        for (int r = 0; r < 2; ++r)
#pragma unroll
            for (int c = 0; c < 7; ++c) c1[r][c] = (f32x4){0, 0, 0, 0};

#pragma unroll
        for (int ks = 0; ks < 4; ++ks) {
            const bool kill = (ks == 3) && (lk != 0);
            const int koff = kill ? 96 : ks * 32 + lk * 8;
            bf16x8 b[7];
#pragma unroll
            for (int tn = 0; tn < 7; ++tn) {
                bf16x8 v = *(const bf16x8*)(Q + (tn * 16 + lr) * CST + koff);
                b[tn] = kill ? zf : v;
            }
#pragma unroll
            for (int tn = 0; tn < 7; ++tn) {
                c1[0][tn] = __builtin_amdgcn_mfma_f32_16x16x32_bf16(xf[0][ks], b[tn], c1[0][tn], 0, 0, 0);
                if (nrow > 1)
                    c1[1][tn] = __builtin_amdgcn_mfma_f32_16x16x32_bf16(xf[1][ks], b[tn], c1[1][tn], 0, 0, 0);
            }
        }
        // HT[o][j] bf16 (clamp j0 < 104); C-cols 100/101 are a_s/a_d
        for (int r = 0; r < nrow; ++r) {
            const int j0 = (r ? row1 : row0) * 16 + 4 * lk;
            if (j0 < 104) {
#pragma unroll
                for (int tn = 0; tn < 7; ++tn) {
                    const int o = tn * 16 + lr;
                    u16x4 p;
                    p.x = f2bf(c1[r][tn].x); p.y = f2bf(c1[r][tn].y);
                    p.z = f2bf(c1[r][tn].z); p.w = f2bf(c1[r][tn].w);
                    *(u16x4*)(HT + o * CST + j0) = p;
                }
            }
            if (lr == 4) *(f32x4*)(sas + j0) = c1[r][6];
            if (lr == 5) *(f32x4*)(sad + j0) = c1[r][6];
        }
        __syncthreads();   // (a) HT/sas/sad ready; all Q reads done

        // ---- issue W[h+1] stage into Q (hidden under E + PV) ----
        if (h < 3) {
            const char* Wn = (const char*)Wbf + (h + 1) * 23552;
            for (int c = w; c < 23; c += 4)
                __builtin_amdgcn_global_load_lds(
                    (const __attribute__((address_space(1))) unsigned int*)(Wn + c * 1024 + l * 16),
                    (__attribute__((address_space(3))) unsigned int*)(smem + 46592 + c * 1024),
                    16, 0, 0);
        }

        // ---- E[i][j] = exp(lrelu(a_d[i]+a_s[j])) bf16 into P; partial sums ----
        if (tid < 200) {
            const int i = tid >> 1, half = tid & 1;
            const float adi = sad[i];
            const int j0 = half * 50;
            unsigned* dst = (unsigned*)(P + i * CST + j0);
            float sum = 0.0f;
            for (int jj = 0; jj < 50; jj += 2) {
                float e0 = __expf(lrelu(adi + sas[j0 + jj]));
                float e1 = __expf(lrelu(adi + sas[j0 + jj + 1]));
                sum += e0 + e1;
                dst[jj >> 1] = ((unsigned)f2bf(e1) << 16) | (unsigned)f2bf(e0);
            }
            sp[half * 112 + i] = sum;
        }
        __syncthreads();   // (b)
        if (tid < 100) ssi[tid] = 1.0f / (sp[tid] + sp[112 + tid]);

        // ---- PV: cp = E * H (A from P, B from HT) ----
        f32x4 cp[2][7];
#pragma unroll
        for (int r = 0; r < 2; ++r)
#pragma unroll
            for (int c = 0; c < 7; ++c) cp[r][c] = (f32x4){0, 0, 0, 0};
#pragma unroll
        for (int ks = 0; ks < 4; ++ks) {
            const bool kill = (ks == 3) && (lk != 0);
            const int koff = kill ? 96 : ks * 32 + lk * 8;
            bf16x8 a0 = *(const bf16x8*)(P + (row0 * 16 + lr) * CST + koff);
            bf16x8 a1 = (nrow > 1) ? *(const bf16x8*)(P + (row1 * 16 + lr) * CST + koff) : a0;
            a0 = kill ? zf : a0;
            a1 = kill ? zf : a1;
#pragma unroll
            for (int tn = 0; tn < 7; ++tn) {
                bf16x8 bb = *(const bf16x8*)(HT + (tn * 16 + lr) * CST + koff);
                bb = kill ? zf : bb;
                cp[0][tn] = __builtin_amdgcn_mfma_f32_16x16x32_bf16(a0, bb, cp[0][tn], 0, 0, 0);
                if (nrow > 1)
                    cp[1][tn] = __builtin_amdgcn_mfma_f32_16x16x32_bf16(a1, bb, cp[1][tn], 0, 0, 0);
            }
        }
        asm volatile("s_waitcnt vmcnt(0)" ::: "memory");   // W[h+1] stage landed
        __syncthreads();   // (c) PV reads done; ssi visible; Q = W[h+1]

        // ---- acc += cp * (1/S_i) ----
        for (int r = 0; r < nrow; ++r) {
            const int i0 = (r ? row1 : row0) * 16 + 4 * lk;
            const f32x4 sv = *(const f32x4*)(ssi + i0);
#pragma unroll
            for (int tn = 0; tn < 7; ++tn)
                acc[r][tn] += cp[r][tn] * sv;
        }
    }

    // ---- epilogue: sOut[o][i] = lrelu(acc*0.25 + bias[o]) + (i==o) ----
    for (int r = 0; r < nrow; ++r) {
        const int i0 = (r ? row1 : row0) * 16 + 4 * lk;
        if (i0 < 104) {
#pragma unroll
            for (int tn = 0; tn < 7; ++tn) {
                const int o = tn * 16 + lr;
                const float b = (o < 100) ? bias[o] : 0.0f;
                f32x4 v;
                v.x = lrelu(acc[r][tn].x * 0.25f + b) + ((i0 + 0) == o ? 1.0f : 0.0f);
                v.y = lrelu(acc[r][tn].y * 0.25f + b) + ((i0 + 1) == o ? 1.0f : 0.0f);
                v.z = lrelu(acc[r][tn].z * 0.25f + b) + ((i0 + 2) == o ? 1.0f : 0.0f);
                v.w = lrelu(acc[r][tn].w * 0.25f + b) + ((i0 + 3) == o ? 1.0f : 0.0f);
                *(f32x4*)(sOut + o * 104 + i0) = v;
            }
        }
    }
    __syncthreads();

    float* __restrict__ outT = out + (size_t)t * 10000u;
    for (int idx = tid; idx < 10000; idx += 256) {
        int o = idx / 100, i2 = idx - o * 100;
        __builtin_nontemporal_store(sOut[o * 104 + i2], outT + idx);
    }
}

extern "C" void kernel_launch(void* const* d_in, const int* in_sizes, int n_in,
                              void* d_out, int out_size, void* d_ws, size_t ws_size,
                              hipStream_t stream) {
    const float* A      = (const float*)d_in[0];
    const float* W      = (const float*)d_in[1];
    const float* attsrc = (const float*)d_in[2];
    const float* attdst = (const float*)d_in[3];
    const float* bias   = (const float*)d_in[4];
    float* outp = (float*)d_out;
    unsigned short* Wbf = (unsigned short*)d_ws;   // 4*23552 = 94208 B

    const int T = in_sizes[0] / 10000;   // 1024

    prep_w<<<4, 128, 0, stream>>>(W, attsrc, attdst, Wbf);

    const int smem_bytes = 72384;
    hipFuncSetAttribute((const void*)gat4,
                        hipFuncAttributeMaxDynamicSharedMemorySize, smem_bytes);
    gat4<<<T, 256, smem_bytes, stream>>>(A, Wbf, bias, outp);
}

// Round 5
// 214.094 us; speedup vs baseline: 1.9297x; 1.9297x over previous
//
#include <hip/hip_runtime.h>

typedef __attribute__((ext_vector_type(8))) short bf16x8;
typedef __attribute__((ext_vector_type(4))) float f32x4;
typedef __attribute__((ext_vector_type(4))) unsigned short u16x4;

#define NEG 0.2f
#define CST 104   // bf16 elems per LDS row (208 B stride; 52dw%32=20 -> clean bank spread)

__device__ __forceinline__ float lrelu(float x) { return x >= 0.0f ? x : NEG * x; }

__device__ __forceinline__ unsigned short f2bf(float x) {
    unsigned u = __builtin_bit_cast(unsigned, x);
    u += 0x7FFFu + ((u >> 16) & 1u);   // RNE
    return (unsigned short)(u >> 16);
}
__device__ __forceinline__ float bf2f(unsigned short v) {
    unsigned u = ((unsigned)v) << 16;
    return __builtin_bit_cast(float, u);
}

// One block per t. 256 threads = 4 waves. 3 blocks/CU (LDS 48832 B).
// LDS: P  [112][104] bf16 @0     : X (until xf hoisted) -> W_h (GEMM-1 B) -> E (PV A), per head
//      HT [112][104] bf16 @23296 : H^T[o][j] per head
//      stats @46592: sas[112] sad[112] ssum[112] satS[112] satD[112] (f32)
//      sOut f32 [112][104] overlays P+HT at the end.
extern "C" __global__ void __launch_bounds__(256, 3)
gat5(const float* __restrict__ A, const float* __restrict__ W,
     const float* __restrict__ att_src, const float* __restrict__ att_dst,
     const float* __restrict__ bias, float* __restrict__ out)
{
    extern __shared__ char smem[];
    unsigned short* P  = (unsigned short*)smem;
    unsigned short* HT = (unsigned short*)(smem + 23296);
    float* sas  = (float*)(smem + 46592);
    float* sad  = sas  + 112;
    float* ssum = sad  + 112;
    float* satS = ssum + 112;
    float* satD = satS + 112;
    float* sOut = (float*)smem;

    const int t   = blockIdx.x;
    const int tid = threadIdx.x;
    const int w   = tid >> 6;
    const int l   = tid & 63;
    const int lr  = l & 15;
    const int lk  = l >> 4;
    const float* __restrict__ At = A + (size_t)t * 10000u;

    // zero P (pads: rows 100-111, cols 100-103 must be 0 for xf)
    for (int i = tid; i < 1456; i += 256) ((f32x4*)smem)[i] = (f32x4){0, 0, 0, 0};
    __syncthreads();

    // stage A_t^T -> P[n][f] bf16 (coalesced float4 reads of n-quads)
    for (int q = tid; q < 2500; q += 256) {
        int f = q / 25, n0 = (q - f * 25) * 4;
        float4 v = *(const float4*)(At + f * 100 + n0);
        P[(n0 + 0) * CST + f] = f2bf(v.x);
        P[(n0 + 1) * CST + f] = f2bf(v.y);
        P[(n0 + 2) * CST + f] = f2bf(v.z);
        P[(n0 + 3) * CST + f] = f2bf(v.w);
    }
    __syncthreads();

    // hoist X fragments to registers (P becomes reusable after next barrier)
    const int nrow = (w < 3) ? 2 : 1;
    const int row0 = w, row1 = w + 4;
    const bf16x8 zf = {0, 0, 0, 0, 0, 0, 0, 0};
    bf16x8 xf[2][4];
#pragma unroll
    for (int ks = 0; ks < 4; ++ks) {
        const bool kill = (ks == 3) && (lk != 0);
        const int koff = kill ? 96 : ks * 32 + lk * 8;
        bf16x8 v0 = *(const bf16x8*)(P + (row0 * 16 + lr) * CST + koff);
        bf16x8 v1 = (nrow > 1) ? *(const bf16x8*)(P + (row1 * 16 + lr) * CST + koff) : v0;
        xf[0][ks] = kill ? zf : v0;
        xf[1][ks] = kill ? zf : v1;
    }

    f32x4 acc[2][7];
#pragma unroll
    for (int r = 0; r < 2; ++r)
#pragma unroll
        for (int c = 0; c < 7; ++c) acc[r][c] = (f32x4){0, 0, 0, 0};

    for (int h = 0; h < 4; ++h) {
        __syncthreads();   // (1) all xf loaded / prev PV+accscale done -> P, stats reusable

        // ---- Wfill: W_h f32 -> P bf16 (rows>=100, cols>=100 zero); stats zero; att load ----
        for (int q = tid; q < 2912; q += 256) {
            int o = q / 26, f0 = (q - o * 26) * 4;
            unsigned lo = 0, hi = 0;
            if (o < 100 && f0 < 100) {
                float4 wv = *(const float4*)(W + (h * 100 + o) * 100 + f0);
                lo = ((unsigned)f2bf(wv.y) << 16) | (unsigned)f2bf(wv.x);
                hi = ((unsigned)f2bf(wv.w) << 16) | (unsigned)f2bf(wv.z);
            }
            *(unsigned*)(P + o * CST + f0)     = lo;
            *(unsigned*)(P + o * CST + f0 + 2) = hi;
        }
        for (int i = tid; i < 336; i += 256) sas[i] = 0.0f;   // sas,sad,ssum contiguous
        if (tid < 100)                        satS[tid]       = att_src[h * 100 + tid];
        else if (tid >= 128 && tid < 228)     satD[tid - 128] = att_dst[h * 100 + tid - 128];
        __syncthreads();   // (2) W ready

        // ---- GEMM-1: c = X * W_h^T (A=xf regs, B=P rows), two N-halves ----
#pragma unroll
        for (int half = 0; half < 2; ++half) {
            const int ntn = half ? 3 : 4;
            f32x4 cfr[2][4];
#pragma unroll
            for (int r = 0; r < 2; ++r)
#pragma unroll
                for (int c = 0; c < 4; ++c) cfr[r][c] = (f32x4){0, 0, 0, 0};
#pragma unroll
            for (int ks = 0; ks < 4; ++ks) {
                const bool kill = (ks == 3) && (lk != 0);
                const int koff = kill ? 96 : ks * 32 + lk * 8;
                bf16x8 b[4];
#pragma unroll
                for (int bb = 0; bb < 4; ++bb) {
                    if (bb < ntn) {
                        bf16x8 v = *(const bf16x8*)(P + ((half * 4 + bb) * 16 + lr) * CST + koff);
                        b[bb] = kill ? zf : v;
                    }
                }
#pragma unroll
                for (int bb = 0; bb < 4; ++bb) {
                    if (bb < ntn) {
                        cfr[0][bb] = __builtin_amdgcn_mfma_f32_16x16x32_bf16(xf[0][ks], b[bb], cfr[0][bb], 0, 0, 0);
                        if (nrow > 1)
                            cfr[1][bb] = __builtin_amdgcn_mfma_f32_16x16x32_bf16(xf[1][ks], b[bb], cfr[1][bb], 0, 0, 0);
                    }
                }
            }
            // write HT[o][j] (j0<104 guard; j0==100 stores zeros needed for PV k-pad)
            for (int r = 0; r < nrow; ++r) {
                const int j0 = (r ? row1 : row0) * 16 + 4 * lk;
                if (j0 < 104) {
#pragma unroll
                    for (int bb = 0; bb < 4; ++bb) {
                        if (bb < ntn) {
                            const int o = (half * 4 + bb) * 16 + lr;
                            u16x4 p;
                            p.x = f2bf(cfr[r][bb].x); p.y = f2bf(cfr[r][bb].y);
                            p.z = f2bf(cfr[r][bb].z); p.w = f2bf(cfr[r][bb].w);
                            *(u16x4*)(HT + o * CST + j0) = p;
                        }
                    }
                }
            }
        }
        __syncthreads();   // (3) HT ready

        // ---- logits: sas[j] += sum_o HT[o][j]*satS[o] (200 threads, 50-o halves, LDS atomics) ----
        if (tid < 200) {
            const int j = tid >> 1, o0 = (tid & 1) * 50;
            float s1 = 0.0f, s2 = 0.0f;
            for (int oo = 0; oo < 50; ++oo) {
                float hv = bf2f(HT[(o0 + oo) * CST + j]);
                s1 = fmaf(hv, satS[o0 + oo], s1);
                s2 = fmaf(hv, satD[o0 + oo], s2);
            }
            atomicAdd(&sas[j], s1);
            atomicAdd(&sad[j], s2);
        }
        __syncthreads();   // (4) sas/sad final

        // ---- E[i][j] = exp(lrelu(sad[i]+sas[j])) bf16 -> P; row sums -> ssum ----
        if (tid < 200) {
            const int i = tid >> 1, j0 = (tid & 1) * 50;
            const float adi = sad[i];
            unsigned* dst = (unsigned*)(P + i * CST + j0);
            float sum = 0.0f;
            for (int jj = 0; jj < 50; jj += 2) {
                float e0 = __expf(lrelu(adi + sas[j0 + jj]));
                float e1 = __expf(lrelu(adi + sas[j0 + jj + 1]));
                sum += e0 + e1;
                dst[jj >> 1] = ((unsigned)f2bf(e1) << 16) | (unsigned)f2bf(e0);
            }
            atomicAdd(&ssum[i], sum);
        }
        __syncthreads();   // (5) E + ssum ready

        // ---- PV: cp = E * H (A=P rows, B=HT rows); acc += cp / ssum ----
#pragma unroll
        for (int half = 0; half < 2; ++half) {
            const int ntn = half ? 3 : 4;
            f32x4 cfr[2][4];
#pragma unroll
            for (int r = 0; r < 2; ++r)
#pragma unroll
                for (int c = 0; c < 4; ++c) cfr[r][c] = (f32x4){0, 0, 0, 0};
#pragma unroll
            for (int ks = 0; ks < 4; ++ks) {
                const bool kill = (ks == 3) && (lk != 0);
                const int koff = kill ? 96 : ks * 32 + lk * 8;
                bf16x8 a0 = *(const bf16x8*)(P + (row0 * 16 + lr) * CST + koff);
                bf16x8 a1 = (nrow > 1) ? *(const bf16x8*)(P + (row1 * 16 + lr) * CST + koff) : a0;
                a0 = kill ? zf : a0;
                a1 = kill ? zf : a1;
                bf16x8 b[4];
#pragma unroll
                for (int bb = 0; bb < 4; ++bb) {
                    if (bb < ntn) {
                        bf16x8 v = *(const bf16x8*)(HT + ((half * 4 + bb) * 16 + lr) * CST + koff);
                        b[bb] = kill ? zf : v;
                    }
                }
#pragma unroll
                for (int bb = 0; bb < 4; ++bb) {
                    if (bb < ntn) {
                        cfr[0][bb] = __builtin_amdgcn_mfma_f32_16x16x32_bf16(a0, b[bb], cfr[0][bb], 0, 0, 0);
                        if (nrow > 1)
                            cfr[1][bb] = __builtin_amdgcn_mfma_f32_16x16x32_bf16(a1, b[bb], cfr[1][bb], 0, 0, 0);
                    }
                }
            }
            for (int r = 0; r < nrow; ++r) {
                const int i0 = (r ? row1 : row0) * 16 + 4 * lk;
                const f32x4 sv = *(const f32x4*)(ssum + i0);
                f32x4 inv;
                inv.x = sv.x > 0.0f ? 1.0f / sv.x : 0.0f;
                inv.y = sv.y > 0.0f ? 1.0f / sv.y : 0.0f;
                inv.z = sv.z > 0.0f ? 1.0f / sv.z : 0.0f;
                inv.w = sv.w > 0.0f ? 1.0f / sv.w : 0.0f;
#pragma unroll
                for (int bb = 0; bb < 4; ++bb)
                    if (bb < ntn) acc[r][half * 4 + bb] += cfr[r][bb] * inv;
            }
        }
    }
    __syncthreads();   // all PV done; P+HT dead -> sOut overlay

    // ---- epilogue: sOut[o][i] = lrelu(acc*0.25 + bias[o]) + (i==o) ----
    for (int r = 0; r < nrow; ++r) {
        const int i0 = (r ? row1 : row0) * 16 + 4 * lk;
        if (i0 < 104) {
#pragma unroll
            for (int tn = 0; tn < 7; ++tn) {
                const int o = tn * 16 + lr;
                const float b = (o < 100) ? bias[o] : 0.0f;
                f32x4 v;
                v.x = lrelu(acc[r][tn].x * 0.25f + b) + ((i0 + 0) == o ? 1.0f : 0.0f);
                v.y = lrelu(acc[r][tn].y * 0.25f + b) + ((i0 + 1) == o ? 1.0f : 0.0f);
                v.z = lrelu(acc[r][tn].z * 0.25f + b) + ((i0 + 2) == o ? 1.0f : 0.0f);
                v.w = lrelu(acc[r][tn].w * 0.25f + b) + ((i0 + 3) == o ? 1.0f : 0.0f);
                *(f32x4*)(sOut + o * 104 + i0) = v;
            }
        }
    }
    __syncthreads();

    // ---- coalesced store out[t][o][i] (float4) ----
    float* __restrict__ outT = out + (size_t)t * 10000u;
    for (int q = tid; q < 2500; q += 256) {
        int o = q / 25, i0 = (q - o * 25) * 4;
        *(float4*)(outT + o * 100 + i0) = *(const float4*)(sOut + o * 104 + i0);
    }
}

extern "C" void kernel_launch(void* const* d_in, const int* in_sizes, int n_in,
                              void* d_out, int out_size, void* d_ws, size_t ws_size,
                              hipStream_t stream) {
    const float* A      = (const float*)d_in[0];
    const float* W      = (const float*)d_in[1];
    const float* attsrc = (const float*)d_in[2];
    const float* attdst = (const float*)d_in[3];
    const float* bias   = (const float*)d_in[4];
    float* outp = (float*)d_out;

    const int T = in_sizes[0] / 10000;   // 1024
    const int smem_bytes = 48832;        // < 64 KB, no opt-in needed
    gat5<<<T, 256, smem_bytes, stream>>>(A, W, attsrc, attdst, bias, outp);
}

// Round 6
// 108.362 us; speedup vs baseline: 3.8125x; 1.9757x over previous
//
#include <hip/hip_runtime.h>

typedef __attribute__((ext_vector_type(8))) short bf16x8;
typedef __attribute__((ext_vector_type(4))) float f32x4;
typedef __attribute__((ext_vector_type(4))) unsigned short u16x4;

#define NEG 0.2f
#define CST 104   // bf16 elems per LDS row (208 B stride)

__device__ __forceinline__ float lrelu(float x) { return x >= 0.0f ? x : NEG * x; }

__device__ __forceinline__ unsigned short f2bf(float x) {
    unsigned u = __builtin_bit_cast(unsigned, x);
    u += 0x7FFFu + ((u >> 16) & 1u);   // RNE
    return (unsigned short)(u >> 16);
}
__device__ __forceinline__ float bf2f(unsigned short v) {
    unsigned u = ((unsigned)v) << 16;
    return __builtin_bit_cast(float, u);
}

// One block per t. 256 threads = 4 waves. 3 blocks/CU (LDS 48832 B).
// LDS: P  [112][104] bf16 @0     : X -> W_h -> alpha (per head)
//      HT [112][104] bf16 @23296 : H^T[o][j] per head
//      stats @46592: sas[112] sad[112] ssum[112] satS[112] satD[112]
//      sOut f32 [112][104] overlays P+HT at the end.
// ALL register arrays statically indexed (rule #20): r-loops unrolled over
// literal 2; wave 3 duplicates its row (row1=row0) with writes suppressed.
extern "C" __global__ void __launch_bounds__(256, 3)
gat6(const float* __restrict__ A, const float* __restrict__ W,
     const float* __restrict__ att_src, const float* __restrict__ att_dst,
     const float* __restrict__ bias, float* __restrict__ out)
{
    extern __shared__ char smem[];
    unsigned short* P  = (unsigned short*)smem;
    unsigned short* HT = (unsigned short*)(smem + 23296);
    float* sas  = (float*)(smem + 46592);
    float* sad  = sas  + 112;
    float* ssum = sad  + 112;
    float* satS = ssum + 112;
    float* satD = satS + 112;
    float* sOut = (float*)smem;

    const int t    = blockIdx.x;
    const int tid  = threadIdx.x;
    const int w    = tid >> 6;
    const int l    = tid & 63;
    const int lr   = l & 15;
    const int lk   = l >> 4;
    const bool HAS2 = (w < 3);
    const int row0 = w;
    const int row1 = HAS2 ? (w + 4) : w;   // w==3 duplicates row 3
    const float* __restrict__ At = A + (size_t)t * 10000u;

    // zero P (X pads must be 0)
    for (int i = tid; i < 1456; i += 256) ((f32x4*)smem)[i] = (f32x4){0, 0, 0, 0};
    __syncthreads();

    // stage A_t^T -> P[n][f] bf16
    for (int q = tid; q < 2500; q += 256) {
        int f = q / 25, n0 = (q - f * 25) * 4;
        float4 v = *(const float4*)(At + f * 100 + n0);
        P[(n0 + 0) * CST + f] = f2bf(v.x);
        P[(n0 + 1) * CST + f] = f2bf(v.y);
        P[(n0 + 2) * CST + f] = f2bf(v.z);
        P[(n0 + 3) * CST + f] = f2bf(v.w);
    }
    __syncthreads();

    // hoist X fragments (static indices)
    const bf16x8 zf = {0, 0, 0, 0, 0, 0, 0, 0};
    bf16x8 xf[2][4];
#pragma unroll
    for (int ks = 0; ks < 4; ++ks) {
        const bool kill = (ks == 3) && (lk != 0);
        const int koff = kill ? 96 : ks * 32 + lk * 8;
        bf16x8 v0 = *(const bf16x8*)(P + (row0 * 16 + lr) * CST + koff);
        bf16x8 v1 = *(const bf16x8*)(P + (row1 * 16 + lr) * CST + koff);
        xf[0][ks] = kill ? zf : v0;
        xf[1][ks] = kill ? zf : v1;
    }

    f32x4 acc[2][7];
#pragma unroll
    for (int r = 0; r < 2; ++r)
#pragma unroll
        for (int c = 0; c < 7; ++c) acc[r][c] = (f32x4){0, 0, 0, 0};

    for (int h = 0; h < 4; ++h) {
        __syncthreads();   // (1) xf hoisted / prev PV done -> P reusable

        // ---- Wfill: W_h -> P bf16 (pads zero); zero stats; att vectors ----
        for (int q = tid; q < 2912; q += 256) {
            int o = q / 26, f0 = (q - o * 26) * 4;
            unsigned lo = 0, hi = 0;
            if (o < 100 && f0 < 100) {
                float4 wv = *(const float4*)(W + (h * 100 + o) * 100 + f0);
                lo = ((unsigned)f2bf(wv.y) << 16) | (unsigned)f2bf(wv.x);
                hi = ((unsigned)f2bf(wv.w) << 16) | (unsigned)f2bf(wv.z);
            }
            *(unsigned*)(P + o * CST + f0)     = lo;
            *(unsigned*)(P + o * CST + f0 + 2) = hi;
        }
        for (int i = tid; i < 336; i += 256) sas[i] = 0.0f;   // sas,sad,ssum
        if (tid < 100)                    satS[tid]       = att_src[h * 100 + tid];
        else if (tid >= 128 && tid < 228) satD[tid - 128] = att_dst[h * 100 + tid - 128];
        __syncthreads();   // (2) W ready

        // ---- GEMM-1: c = X * W_h^T, two N-halves, static c arrays ----
#pragma unroll
        for (int half = 0; half < 2; ++half) {
            const int ntn = half ? 3 : 4;
            f32x4 c0[4], c1[4];
#pragma unroll
            for (int c = 0; c < 4; ++c) { c0[c] = (f32x4){0,0,0,0}; c1[c] = (f32x4){0,0,0,0}; }
#pragma unroll
            for (int ks = 0; ks < 4; ++ks) {
                const bool kill = (ks == 3) && (lk != 0);
                const int koff = kill ? 96 : ks * 32 + lk * 8;
                bf16x8 b[4];
#pragma unroll
                for (int bb = 0; bb < 4; ++bb)
                    if (bb < ntn) {
                        bf16x8 v = *(const bf16x8*)(P + ((half * 4 + bb) * 16 + lr) * CST + koff);
                        b[bb] = kill ? zf : v;
                    }
#pragma unroll
                for (int bb = 0; bb < 4; ++bb)
                    if (bb < ntn) {
                        c0[bb] = __builtin_amdgcn_mfma_f32_16x16x32_bf16(xf[0][ks], b[bb], c0[bb], 0, 0, 0);
                        c1[bb] = __builtin_amdgcn_mfma_f32_16x16x32_bf16(xf[1][ks], b[bb], c1[bb], 0, 0, 0);
                    }
            }
            // HT writes + logit columns (static indices, runtime guards only)
            {
                const int j0 = row0 * 16 + 4 * lk;    // <= 60, always in range
#pragma unroll
                for (int bb = 0; bb < 4; ++bb)
                    if (bb < ntn) {
                        const int o = (half * 4 + bb) * 16 + lr;
                        u16x4 p;
                        p.x = f2bf(c0[bb].x); p.y = f2bf(c0[bb].y);
                        p.z = f2bf(c0[bb].z); p.w = f2bf(c0[bb].w);
                        *(u16x4*)(HT + o * CST + j0) = p;
                    }
            }
            if (HAS2) {
                const int j0 = row1 * 16 + 4 * lk;    // up to 108
                if (j0 < 104) {
#pragma unroll
                    for (int bb = 0; bb < 4; ++bb)
                        if (bb < ntn) {
                            const int o = (half * 4 + bb) * 16 + lr;
                            u16x4 p;
                            p.x = f2bf(c1[bb].x); p.y = f2bf(c1[bb].y);
                            p.z = f2bf(c1[bb].z); p.w = f2bf(c1[bb].w);
                            *(u16x4*)(HT + o * CST + j0) = p;
                        }
                }
            }
        }
        __syncthreads();   // (3) HT ready

        // ---- logits: sas[j]/sad[j] via partial dots + LDS atomics ----
        if (tid < 200) {
            const int j = tid >> 1, o0 = (tid & 1) * 50;
            float s1 = 0.0f, s2 = 0.0f;
            for (int oo = 0; oo < 50; ++oo) {
                float hv = bf2f(HT[(o0 + oo) * CST + j]);
                s1 = fmaf(hv, satS[o0 + oo], s1);
                s2 = fmaf(hv, satD[o0 + oo], s2);
            }
            atomicAdd(&sas[j], s1);
            atomicAdd(&sad[j], s2);
        }
        __syncthreads();   // (4) sas/sad final

        // ---- row sums: ssum[i] = sum_j exp(lrelu(sad[i]+sas[j])) ----
        if (tid < 200) {
            const int i = tid >> 1, j0 = (tid & 1) * 50;
            const float adi = sad[i];
            float sum = 0.0f;
            for (int jj = 0; jj < 50; ++jj) sum += __expf(lrelu(adi + sas[j0 + jj]));
            atomicAdd(&ssum[i], sum);
        }
        __syncthreads();   // (5) ssum final

        // ---- alpha[i][j] = exp(...)/ssum[i] bf16 -> P (pre-normalized) ----
        if (tid < 200) {
            const int i = tid >> 1, j0 = (tid & 1) * 50;
            const float adi = sad[i];
            const float inv = 1.0f / ssum[i];
            unsigned* dst = (unsigned*)(P + i * CST + j0);
            for (int jj = 0; jj < 50; jj += 2) {
                float e0 = __expf(lrelu(adi + sas[j0 + jj]))     * inv;
                float e1 = __expf(lrelu(adi + sas[j0 + jj + 1])) * inv;
                dst[jj >> 1] = ((unsigned)f2bf(e1) << 16) | (unsigned)f2bf(e0);
            }
        }
        __syncthreads();   // (6) alpha ready

        // ---- PV: acc += alpha * H (direct C accumulation, static indices) ----
#pragma unroll
        for (int half = 0; half < 2; ++half) {
            const int ntn = half ? 3 : 4;
#pragma unroll
            for (int ks = 0; ks < 4; ++ks) {
                const bool kill = (ks == 3) && (lk != 0);
                const int koff = kill ? 96 : ks * 32 + lk * 8;
                bf16x8 a0 = *(const bf16x8*)(P + (row0 * 16 + lr) * CST + koff);
                bf16x8 a1 = *(const bf16x8*)(P + (row1 * 16 + lr) * CST + koff);
                a0 = kill ? zf : a0;
                a1 = kill ? zf : a1;
                bf16x8 b[4];
#pragma unroll
                for (int bb = 0; bb < 4; ++bb)
                    if (bb < ntn) {
                        bf16x8 v = *(const bf16x8*)(HT + ((half * 4 + bb) * 16 + lr) * CST + koff);
                        b[bb] = kill ? zf : v;
                    }
#pragma unroll
                for (int bb = 0; bb < 4; ++bb)
                    if (bb < ntn) {
                        acc[0][half * 4 + bb] = __builtin_amdgcn_mfma_f32_16x16x32_bf16(a0, b[bb], acc[0][half * 4 + bb], 0, 0, 0);
                        acc[1][half * 4 + bb] = __builtin_amdgcn_mfma_f32_16x16x32_bf16(a1, b[bb], acc[1][half * 4 + bb], 0, 0, 0);
                    }
            }
        }
    }
    __syncthreads();   // all PV done; P+HT dead -> sOut overlay

    // ---- epilogue: sOut[o][i] = lrelu(acc*0.25 + bias[o]) + (i==o) ----
    {
        const int i0 = row0 * 16 + 4 * lk;   // <= 60
#pragma unroll
        for (int tn = 0; tn < 7; ++tn) {
            const int o = tn * 16 + lr;
            const float b = (o < 100) ? bias[o] : 0.0f;
            f32x4 v;
            v.x = lrelu(acc[0][tn].x * 0.25f + b) + ((i0 + 0) == o ? 1.0f : 0.0f);
            v.y = lrelu(acc[0][tn].y * 0.25f + b) + ((i0 + 1) == o ? 1.0f : 0.0f);
            v.z = lrelu(acc[0][tn].z * 0.25f + b) + ((i0 + 2) == o ? 1.0f : 0.0f);
            v.w = lrelu(acc[0][tn].w * 0.25f + b) + ((i0 + 3) == o ? 1.0f : 0.0f);
            *(f32x4*)(sOut + o * 104 + i0) = v;
        }
    }
    if (HAS2) {
        const int i0 = row1 * 16 + 4 * lk;   // up to 108
        if (i0 < 104) {
#pragma unroll
            for (int tn = 0; tn < 7; ++tn) {
                const int o = tn * 16 + lr;
                const float b = (o < 100) ? bias[o] : 0.0f;
                f32x4 v;
                v.x = lrelu(acc[1][tn].x * 0.25f + b) + ((i0 + 0) == o ? 1.0f : 0.0f);
                v.y = lrelu(acc[1][tn].y * 0.25f + b) + ((i0 + 1) == o ? 1.0f : 0.0f);
                v.z = lrelu(acc[1][tn].z * 0.25f + b) + ((i0 + 2) == o ? 1.0f : 0.0f);
                v.w = lrelu(acc[1][tn].w * 0.25f + b) + ((i0 + 3) == o ? 1.0f : 0.0f);
                *(f32x4*)(sOut + o * 104 + i0) = v;
            }
        }
    }
    __syncthreads();

    // ---- coalesced store out[t][o][i] ----
    float* __restrict__ outT = out + (size_t)t * 10000u;
    for (int q = tid; q < 2500; q += 256) {
        int o = q / 25, i0 = (q - o * 25) * 4;
        *(float4*)(outT + o * 100 + i0) = *(const float4*)(sOut + o * 104 + i0);
    }
}

extern "C" void kernel_launch(void* const* d_in, const int* in_sizes, int n_in,
                              void* d_out, int out_size, void* d_ws, size_t ws_size,
                              hipStream_t stream) {
    const float* A      = (const float*)d_in[0];
    const float* W      = (const float*)d_in[1];
    const float* attsrc = (const float*)d_in[2];
    const float* attdst = (const float*)d_in[3];
    const float* bias   = (const float*)d_in[4];
    float* outp = (float*)d_out;

    const int T = in_sizes[0] / 10000;   // 1024
    const int smem_bytes = 48832;
    gat6<<<T, 256, smem_bytes, stream>>>(A, W, attsrc, attdst, bias, outp);
}